// Round 12
// baseline (477.411 us; speedup 1.0000x reference)
//
#include <hip/hip_runtime.h>
#include <math.h>

#define BB   64
#define NTOK 197
#define CC   768
#define HH   12
#define DH   64
#define MTOT (BB * NTOK)          // 12608
#define MPAD 12672                // 99*128
#define LEFT 138

// d_out layout (floats, concatenated in return order)
#define XOUT_OFF  0
#define INDEX_OFF 9682944         // B*N*C
#define IDX_OFF   16465920        // + B*138*C
#define CLS_OFF   16474752        // + B*138
#define LT_OFF    16487296        // + B*196

typedef short s8v __attribute__((ext_vector_type(8)));
typedef short s4v __attribute__((ext_vector_type(4)));
typedef float f4v __attribute__((ext_vector_type(4)));

#define GLOAD16(g, l) __builtin_amdgcn_global_load_lds( \
    (const __attribute__((address_space(1))) unsigned int*)(g), \
    (__attribute__((address_space(3))) unsigned int*)(l), 16, 0, 0)

__device__ __forceinline__ unsigned short f2bf(float f) {
    union { float f; unsigned int i; } x; x.f = f;
    unsigned int r = x.i + 0x7FFFu + ((x.i >> 16) & 1u);   // RNE
    return (unsigned short)(r >> 16);
}

// ---------------------------------------------------------------------------
// fp32 [M,768] -> bf16 [M,768]
// ---------------------------------------------------------------------------
__global__ __launch_bounds__(256)
void convert_x(const float* __restrict__ in, unsigned short* __restrict__ outb)
{
    size_t i = ((size_t)blockIdx.x * 256 + threadIdx.x) * 8;
    float4 a = *(const float4*)(in + i);
    float4 b = *(const float4*)(in + i + 4);
    s8v r;
    r[0] = (short)f2bf(a.x); r[1] = (short)f2bf(a.y);
    r[2] = (short)f2bf(a.z); r[3] = (short)f2bf(a.w);
    r[4] = (short)f2bf(b.x); r[5] = (short)f2bf(b.y);
    r[6] = (short)f2bf(b.z); r[7] = (short)f2bf(b.w);
    *(s8v*)(outb + i) = r;
}

// ---------------------------------------------------------------------------
// fp32 W [768,N] -> bf16 W^T [N,768].  bj<72 -> qkv_w (N=2304), else proj_w.
// ---------------------------------------------------------------------------
__global__ __launch_bounds__(256)
void transpose_w2(const float* __restrict__ inq, const float* __restrict__ inp,
                  unsigned short* __restrict__ outq, unsigned short* __restrict__ outp)
{
    __shared__ float tile[32][33];
    const int bi = blockIdx.x;
    int bj = blockIdx.y;
    const float* in; unsigned short* outb; int N;
    if (bj < 72) { in = inq; outb = outq; N = 2304; }
    else         { bj -= 72; in = inp; outb = outp; N = 768; }
    const int tx = threadIdx.x & 31, ty = threadIdx.x >> 5;
#pragma unroll
    for (int r = ty; r < 32; r += 8)
        tile[r][tx] = in[(size_t)(bi * 32 + r) * N + bj * 32 + tx];
    __syncthreads();
#pragma unroll
    for (int r = ty; r < 32; r += 8)
        outb[(size_t)(bj * 32 + r) * 768 + bi * 32 + tx] = f2bf(tile[tx][r]);
}

// ---------------------------------------------------------------------------
// bf16 MFMA GEMM (rt0/nrt kept; QKV launched merged again).
// ---------------------------------------------------------------------------
__global__ __launch_bounds__(256, 3)
void gemm_bf16(const unsigned short* __restrict__ A, const unsigned short* __restrict__ BT,
               const float* __restrict__ bias, int ncolt, int mode, int rt0, int nrt,
               unsigned short* __restrict__ outb, float* __restrict__ outf)
{
    const int id = blockIdx.x;
    const int xcd = id & 7;
    const int t = id >> 3;
    const int ct = t % ncolt, s = t / ncolt;
    const int rt = s * 8 + xcd;
    if (rt >= nrt) return;
    const int m0 = (rt0 + rt) * 128, n0 = ct * 128;

    const int tid = threadIdx.x;
    const int wave = tid >> 6, lane = tid & 63;
    const int quad = lane >> 4, l16 = lane & 15;
    const int rowbase = (wave >> 1) * 64, colbase = (wave & 1) * 64;
    __shared__ __align__(16) short As[128 * 64];
    __shared__ __align__(16) short Bs[128 * 64];

    const int rA   = lane >> 3;
    const int gcol = ((lane & 7) ^ rA) * 8;
    unsigned int agof[4], bgof[4];             // 32-bit element offsets
#pragma unroll
    for (int i = 0; i < 4; ++i) {
        int c = wave * 4 + i;
        agof[i] = (unsigned int)((m0 + c * 8 + rA) * 768 + gcol);
        bgof[i] = (unsigned int)((n0 + c * 8 + rA) * 768 + gcol);
    }
    int aoff[4], boff[4];
#pragma unroll
    for (int i = 0; i < 4; ++i) {
        aoff[i] = (rowbase + i * 16 + l16) * 64 + ((quad ^ (l16 & 7)) * 8);
        boff[i] = (colbase + i * 16 + l16) * 64 + ((quad ^ (l16 & 7)) * 8);
    }

    f4v acc[4][4];
#pragma unroll
    for (int i = 0; i < 4; ++i)
#pragma unroll
        for (int j = 0; j < 4; ++j) acc[i][j] = (f4v)0.f;

    for (int k0 = 0; k0 < 768; k0 += 64) {
#pragma unroll
        for (int i = 0; i < 4; ++i) {
            int c = wave * 4 + i;
            GLOAD16(A  + agof[i] + k0, &As[c * 512]);
            GLOAD16(BT + bgof[i] + k0, &Bs[c * 512]);
        }
        __syncthreads();
#pragma unroll
        for (int ks = 0; ks < 2; ++ks) {
            const int x = ks * 32;
            s8v af[4], bf[4];
#pragma unroll
            for (int i = 0; i < 4; ++i) af[i] = *(const s8v*)&As[aoff[i] ^ x];
#pragma unroll
            for (int j = 0; j < 4; ++j) bf[j] = *(const s8v*)&Bs[boff[j] ^ x];
#pragma unroll
            for (int i = 0; i < 4; ++i)
#pragma unroll
                for (int j = 0; j < 4; ++j)
                    acc[i][j] = __builtin_amdgcn_mfma_f32_16x16x32_bf16(bf[j], af[i], acc[i][j], 0, 0, 0);
        }
        __syncthreads();
    }

    const int ncols = mode ? 768 : 2304;
#pragma unroll
    for (int i = 0; i < 4; ++i) {
        const int m = m0 + rowbase + i * 16 + l16;
        if (m >= MTOT) continue;
#pragma unroll
        for (int j = 0; j < 4; ++j) {
            const int nb = n0 + colbase + j * 16 + quad * 4;
            float4 b4 = *(const float4*)&bias[nb];
            if (mode == 1) {
                float4 r;
                r.x = acc[i][j][0] + b4.x; r.y = acc[i][j][1] + b4.y;
                r.z = acc[i][j][2] + b4.z; r.w = acc[i][j][3] + b4.w;
                *(float4*)(outf + (size_t)m * ncols + nb) = r;
            } else {
                s4v r;
                r[0] = (short)f2bf(acc[i][j][0] + b4.x);
                r[1] = (short)f2bf(acc[i][j][1] + b4.y);
                r[2] = (short)f2bf(acc[i][j][2] + b4.z);
                r[3] = (short)f2bf(acc[i][j][3] + b4.w);
                *(s4v*)(outb + (size_t)m * ncols + nb) = r;
            }
        }
    }
}

// ---------------------------------------------------------------------------
// V^T materialization (unchanged): qkvbf V [b,tok,h,d] -> vt [bh][d][224],
// bf16, zero-padded tok>=197.
// ---------------------------------------------------------------------------
#define VTS 224

__global__ __launch_bounds__(256)
void transpose_v(const unsigned short* __restrict__ qkv, unsigned short* __restrict__ vt)
{
    __shared__ short tile[32][33];
    const int bx = blockIdx.x;           // tok tile 0..6
    const int by = blockIdx.y;           // d tile 0..1
    const int bh = blockIdx.z;           // 0..767
    const int b = bh / HH, h = bh - b * HH;
    const int tx = threadIdx.x & 31, ty = threadIdx.x >> 5;
    const unsigned short* vin = qkv + (size_t)b * NTOK * 2304 + 1536 + h * DH;
#pragma unroll
    for (int r = ty; r < 32; r += 8) {
        const int tok = bx * 32 + r;
        tile[r][tx] = (tok < NTOK) ? (short)vin[(size_t)tok * 2304 + by * 32 + tx] : (short)0;
    }
    __syncthreads();
#pragma unroll
    for (int r = ty; r < 32; r += 8) {
        const int d = by * 32 + r;
        vt[((size_t)bh * DH + d) * VTS + bx * 32 + tx] = tile[tx][r];
    }
}

// ---------------------------------------------------------------------------
// MFMA attention, round-17 "attn8": ONE 512-thread block per head, 8 waves,
// strips stride-8 (waves 0-4: 2 strips, 5-7: 1). Fixes mfma4's two structural
// costs: K staged 4x per head (now read from global, shared by 8 waves via
// L1/L2 -> fetched ~once) and 4 separate blocks with barriers (now ZERO
// __syncthreads; Ps is wave-private; within-wave LDS ordering is lgkmcnt).
// No V^T reg-prefetch (kept regs <=128 for 2 blocks/CU = 16 waves/CU,
// ~3x mfma4's 5.6). Per-strip body bit-identical: K from global as R5/R7,
// V^T from vt as R10/R11.
// ---------------------------------------------------------------------------
#define PSTR 226

__global__ __launch_bounds__(512, 4)
void attn8(const unsigned short* __restrict__ qkv, const unsigned short* __restrict__ vt,
           unsigned short* __restrict__ attnbf)
{
    const int bh = blockIdx.x;           // 0..767
    const int b = bh / HH, h = bh - b * HH;
    const int tid = threadIdx.x;
    const int wave = tid >> 6, lane = tid & 63;
    const int quad = lane >> 4, l16 = lane & 15;
    __shared__ short Ps[8][16 * PSTR];   // 57.9 KB, wave-private slices

    const unsigned short* qg = qkv + (size_t)b * NTOK * 2304 + h * DH;
    const unsigned short* kg = qg + 768;
    const unsigned short* vtb = vt + (size_t)bh * DH * VTS;

    for (int strip = wave; strip < 13; strip += 8) {
        const int mq = min(strip * 16 + l16, NTOK - 1);
        const s8v aq0 = *(const s8v*)(qg + (size_t)mq * 2304 + quad * 8);
        const s8v aq1 = *(const s8v*)(qg + (size_t)mq * 2304 + 32 + quad * 8);

        f4v sacc[14];
#pragma unroll
        for (int j = 0; j < 14; ++j) sacc[j] = (f4v)0.f;
        __builtin_amdgcn_s_setprio(1);
#pragma unroll
        for (int j = 0; j < 14; ++j) {
            const int kt = min(j * 16 + l16, NTOK - 1);
            s8v bk0 = *(const s8v*)(kg + (size_t)kt * 2304 + quad * 8);
            s8v bk1 = *(const s8v*)(kg + (size_t)kt * 2304 + 32 + quad * 8);
            sacc[j] = __builtin_amdgcn_mfma_f32_16x16x32_bf16(bk0, aq0, sacc[j], 0, 0, 0);
            sacc[j] = __builtin_amdgcn_mfma_f32_16x16x32_bf16(bk1, aq1, sacc[j], 0, 0, 0);
        }
        __builtin_amdgcn_s_setprio(0);

        float mx = -1e30f;
#pragma unroll
        for (int j = 0; j < 14; ++j)
#pragma unroll
            for (int r = 0; r < 4; ++r) {
                const int key = j * 16 + quad * 4 + r;
                float s = (key < NTOK) ? sacc[j][r] * 0.125f : -1e30f;
                sacc[j][r] = s;
                mx = fmaxf(mx, s);
            }
        mx = fmaxf(mx, __shfl_xor(mx, 16, 64));
        mx = fmaxf(mx, __shfl_xor(mx, 32, 64));

        float sm = 0.f;
#pragma unroll
        for (int j = 0; j < 14; ++j) {
            s4v pk;
#pragma unroll
            for (int r = 0; r < 4; ++r) {
                const int key = j * 16 + quad * 4 + r;
                float p = (key < NTOK) ? __expf(sacc[j][r] - mx) : 0.f;
                sm += p;
                pk[r] = (short)f2bf(p);
            }
            *(s4v*)&Ps[wave][l16 * PSTR + j * 16 + quad * 4] = pk;
        }
        sm += __shfl_xor(sm, 16, 64);
        sm += __shfl_xor(sm, 32, 64);
        const float rcp = 1.f / sm;

        f4v oacc[4];
#pragma unroll
        for (int j = 0; j < 4; ++j) oacc[j] = (f4v)0.f;
        __builtin_amdgcn_s_setprio(1);
#pragma unroll
        for (int t = 0; t < 7; ++t) {
            const int ko = t * 32 + quad * 8;
            s8v ap = *(const s8v*)&Ps[wave][l16 * PSTR + ko];
#pragma unroll
            for (int j = 0; j < 4; ++j) {
                s8v bv = *(const s8v*)(vtb + (size_t)(j * 16 + l16) * VTS + ko);
                oacc[j] = __builtin_amdgcn_mfma_f32_16x16x32_bf16(bv, ap, oacc[j], 0, 0, 0);
            }
        }
        __builtin_amdgcn_s_setprio(0);
        const int qrow = strip * 16 + l16;
        if (qrow < NTOK) {
#pragma unroll
            for (int j = 0; j < 4; ++j) {
                s4v o4;
#pragma unroll
                for (int r = 0; r < 4; ++r) o4[r] = (short)f2bf(oacc[j][r] * rcp);
                *(s4v*)&attnbf[((size_t)b * NTOK + qrow) * 768 + h * DH + j * 16 + quad * 4] = o4;
            }
        }
    }
}

// ---------------------------------------------------------------------------
// Exact fp32 cls path (unchanged). ASSOCIATION ORDER IS LOAD-BEARING.
// ---------------------------------------------------------------------------
#define QCH  64
#define BGRP 8

__global__ __launch_bounds__(256)
void qr_kernel(const float* __restrict__ x, const float* __restrict__ qkv_w,
               const float* __restrict__ qkv_b, float* __restrict__ rws,
               float* __restrict__ bconst)
{
    const int h  = blockIdx.x;          // 0..11
    const int b0 = blockIdx.y * BGRP;   // 0,8,...,56
    const int tid = threadIdx.x;
    __shared__ float x0s[BGRP][CC];     // 24 KB
    __shared__ float wbuf[2][QCH * DH]; // 32 KB
    __shared__ float q0s[BGRP][DH];     // 2 KB

    for (int u = tid; u < BGRP * CC; u += 256) {
        int b = u / CC, c = u - b * CC;
        x0s[b][c] = x[(size_t)(b0 + b) * NTOK * CC + c];
    }
    for (int u = tid; u < QCH * DH; u += 256) {
        int cc = u >> 6, dd = u & 63;
        wbuf[0][u] = qkv_w[(size_t)cc * 2304 + h * DH + dd];
    }
    __syncthreads();

    const int d  = tid & 63;
    const int bA = tid >> 6;            // 0..3
    const int bB = bA + 4;
    float accA = qkv_b[h * DH + d];
    float accB = qkv_b[h * DH + d];
    for (int k = 0; k < CC / QCH; ++k) {
        const int cur = k & 1;
        if (k + 1 < CC / QCH) {
            const int cbase = (k + 1) * QCH;
            for (int u = tid; u < QCH * DH; u += 256) {
                int cc = u >> 6, dd = u & 63;
                wbuf[cur ^ 1][u] = qkv_w[(size_t)(cbase + cc) * 2304 + h * DH + dd];
            }
        }
        const int cb = k * QCH;
#pragma unroll
        for (int cc = 0; cc < QCH; ++cc) {
            const float wv = wbuf[cur][cc * 64 + d];
            accA = fmaf(x0s[bA][cb + cc], wv, accA);
            accB = fmaf(x0s[bB][cb + cc], wv, accB);
        }
        __syncthreads();
    }
    q0s[bA][d] = accA;
    q0s[bB][d] = accB;
    __syncthreads();

    if (tid < BGRP) {
        float acc3 = 0.f;
        for (int dd = 0; dd < DH; ++dd) acc3 += q0s[tid][dd] * qkv_b[CC + h * DH + dd];
        bconst[(b0 + tid) * HH + h] = acc3;
    }

    for (int c = tid; c < CC; c += 256) {
        const float* wrow = qkv_w + (size_t)c * 2304 + CC + h * DH;
        float acc2[BGRP];
#pragma unroll
        for (int b = 0; b < BGRP; ++b) acc2[b] = 0.f;
#pragma unroll
        for (int dd = 0; dd < DH; dd += 4) {
            float4 w4 = *(const float4*)(wrow + dd);
#pragma unroll
            for (int b = 0; b < BGRP; ++b) {
                acc2[b] = fmaf(w4.x, q0s[b][dd + 0], acc2[b]);
                acc2[b] = fmaf(w4.y, q0s[b][dd + 1], acc2[b]);
                acc2[b] = fmaf(w4.z, q0s[b][dd + 2], acc2[b]);
                acc2[b] = fmaf(w4.w, q0s[b][dd + 3], acc2[b]);
            }
        }
#pragma unroll
        for (int b = 0; b < BGRP; ++b)
            rws[((size_t)(b0 + b) * HH + h) * CC + c] = acc2[b];
    }
}

// cls_s (round-16 dbuf version, unchanged).
#define CTOK 22
#define CCH  96
#define CSTR 100

__global__ __launch_bounds__(256)
void cls_s(const float* __restrict__ x, const float* __restrict__ rws,
           const float* __restrict__ bconst, float* __restrict__ sws)
{
    const int b = blockIdx.y;
    const int tid = threadIdx.x;
    __shared__ __align__(16) float rl[HH * 772];          // 37.1 KB
    __shared__ float bcs[HH];
    __shared__ __align__(16) float xt[2][CTOK * CSTR];    // 17.6 KB

    for (int u = tid; u < HH * CC; u += 256) {
        int h = u / CC, c = u - h * CC;
        rl[h * 772 + c] = rws[(size_t)b * HH * CC + u];
    }
    if (tid < HH) bcs[tid] = bconst[b * HH + tid];

    const int pair0 = blockIdx.x * 256;
    const int tok0 = pair0 / HH;
    const int local = pair0 + tid;
    const int tok = local / HH;
    const int h = local - tok * HH;
    const bool act = (local < NTOK * HH);
    const int trow = tok - tok0;

    for (int u = tid; u < CTOK * (CCH / 4); u += 256) {
        const int row = u / (CCH / 4), c4 = u - row * (CCH / 4);
        const int tk = tok0 + row;
        if (tk < NTOK)
            *(float4*)&xt[0][row * CSTR + c4 * 4] =
                *(const float4*)(x + ((size_t)b * NTOK + tk) * CC + c4 * 4);
    }
    __syncthreads();

    float acc = 0.f;
    for (int ch = 0; ch < CC / CCH; ++ch) {
        const int cur = ch & 1;
        if (ch + 1 < CC / CCH) {
            const int cb = (ch + 1) * CCH;
            for (int u = tid; u < CTOK * (CCH / 4); u += 256) {
                const int row = u / (CCH / 4), c4 = u - row * (CCH / 4);
                const int tk = tok0 + row;
                if (tk < NTOK)
                    *(float4*)&xt[cur ^ 1][row * CSTR + c4 * 4] =
                        *(const float4*)(x + ((size_t)b * NTOK + tk) * CC + cb + c4 * 4);
            }
        }
        if (act) {
            const float* xr = &xt[cur][trow * CSTR];
            const float* rp = rl + h * 772 + ch * CCH;
#pragma unroll
            for (int c = 0; c < CCH; c += 4) {
                float4 x4 = *(const float4*)(xr + c);
                float4 r4 = *(const float4*)(rp + c);
                acc = fmaf(x4.x, r4.x, acc);
                acc = fmaf(x4.y, r4.y, acc);
                acc = fmaf(x4.z, r4.z, acc);
                acc = fmaf(x4.w, r4.w, acc);
            }
        }
        __syncthreads();
    }
    if (act)
        sws[((size_t)b * HH + h) * NTOK + tok] = (acc + bcs[h]) * 0.125f;
}

// cls_topk: exact softmax/mean/bitonic code; INDEX fill in write_index.
__global__ __launch_bounds__(256)
void cls_topk(const float* __restrict__ sws, float* __restrict__ out, int write_lt)
{
    const int b = blockIdx.x, tid = threadIdx.x;
    const int wave = tid >> 6, lane = tid & 63;
    __shared__ float sbuf[HH][208];
    __shared__ float pm[4][208];
    __shared__ float vals[256];
    __shared__ int   idxs[256];

    for (int jj = lane; jj < 208; jj += 64) pm[wave][jj] = 0.f;
    if (tid < NTOK) {
#pragma unroll
        for (int h = 0; h < HH; ++h)
            sbuf[h][tid] = sws[((size_t)b * HH + h) * NTOK + tid];
    }
    __syncthreads();

    for (int h = wave; h < HH; h += 4) {
        float sv[4], ev[4];
        float mx = -1e30f;
#pragma unroll
        for (int t = 0; t < 4; ++t) {
            int j = lane + 64 * t;
            sv[t] = (j < NTOK) ? sbuf[h][j] : -1e30f;
            mx = fmaxf(mx, sv[t]);
        }
#pragma unroll
        for (int off = 1; off < 64; off <<= 1) mx = fmaxf(mx, __shfl_xor(mx, off, 64));
        float sm = 0.f;
#pragma unroll
        for (int t = 0; t < 4; ++t) {
            int j = lane + 64 * t;
            ev[t] = (j < NTOK) ? expf(sv[t] - mx) : 0.f;
            sm += ev[t];
        }
#pragma unroll
        for (int off = 1; off < 64; off <<= 1) sm += __shfl_xor(sm, off, 64);
#pragma unroll
        for (int t = 0; t < 4; ++t) {
            int j = lane + 64 * t;
            if (j < NTOK) pm[wave][j] += ev[t] / sm;
        }
    }
    __syncthreads();

    float v = -INFINITY;
    int id = 256 + tid;
    if (tid < NTOK - 1) {
        int j = tid + 1;
        float s = ((pm[0][j] + pm[1][j]) + (pm[2][j] + pm[3][j])) * (1.f / 12.f);
        v = s; id = tid;
        out[CLS_OFF + (size_t)b * (NTOK - 1) + tid] = s;
    }
    vals[tid] = v; idxs[tid] = id;
    __syncthreads();

    for (int k = 2; k <= 256; k <<= 1) {
        for (int j = k >> 1; j > 0; j >>= 1) {
            int ixj = tid ^ j;
            if (ixj > tid) {
                float va = vals[tid], vb2 = vals[ixj];
                int ia = idxs[tid], ib = idxs[ixj];
                bool aLess = (va > vb2) || (va == vb2 && ia < ib);
                bool dir = ((tid & k) == 0);
                if (dir != aLess) {
                    vals[tid] = vb2; vals[ixj] = va;
                    idxs[tid] = ib;  idxs[ixj] = ia;
                }
            }
            __syncthreads();
        }
    }

    if (tid < LEFT) out[IDX_OFF + (size_t)b * LEFT + tid] = (float)idxs[tid];
    if (write_lt && b == 0 && tid == 0) out[LT_OFF] = (float)LEFT;
}

// write_index: broadcast idx[row] across 768 channels.
__global__ __launch_bounds__(64)
void write_index(const float* __restrict__ idx_in, float* __restrict__ out)
{
    const int row = blockIdx.x;              // b*LEFT + t
    const float v = idx_in[row];
    const int tid = threadIdx.x;
    float4 r; r.x = v; r.y = v; r.z = v; r.w = v;
#pragma unroll
    for (int i = 0; i < 3; ++i)
        *(float4*)(out + INDEX_OFF + (size_t)row * CC + (tid + 64 * i) * 4) = r;
}

// ---------------------------------------------------------------------------
extern "C" void kernel_launch(void* const* d_in, const int* in_sizes, int n_in,
                              void* d_out, int out_size, void* d_ws, size_t ws_size,
                              hipStream_t stream)
{
    const float* x      = (const float*)d_in[0];
    const float* qkv_w  = (const float*)d_in[1];
    const float* qkv_b  = (const float*)d_in[2];
    const float* proj_w = (const float*)d_in[3];
    const float* proj_b = (const float*)d_in[4];
    float* out = (float*)d_out;

    char* w = (char*)d_ws;
    unsigned short* xbf   = (unsigned short*)w; w += (size_t)MPAD * CC * 2;
    unsigned short* wt1   = (unsigned short*)w; w += (size_t)3 * CC * CC * 2;
    unsigned short* wt2   = (unsigned short*)w; w += (size_t)CC * CC * 2;
    unsigned short* qkvbf = (unsigned short*)w; w += (size_t)MTOT * 3 * CC * 2;
    unsigned short* atbf  = (unsigned short*)w; w += (size_t)MPAD * CC * 2;
    float* rws    = (float*)w; w += (size_t)BB * HH * CC * 4;
    float* bconst = (float*)w; w += (size_t)BB * HH * 4;
    float* sws    = (float*)w; w += (size_t)BB * HH * NTOK * 4;
    // vt aliases xbf+wt1 (22.0MB <= 26.5MB): both dead after the QKV GEMM,
    // and transpose_v runs after it (stream-serial).
    unsigned short* vtbf  = (unsigned short*)d_ws;

    // Cls path first: x is L3-resident right after convert_x reads it.
    convert_x<<<dim3(4728), 256, 0, stream>>>(x, xbf);
    transpose_w2<<<dim3(24, 96), 256, 0, stream>>>(qkv_w, proj_w, wt1, wt2);
    qr_kernel<<<dim3(HH, BB / BGRP), 256, 0, stream>>>(x, qkv_w, qkv_b, rws, bconst);
    cls_s<<<dim3(10, 64), 256, 0, stream>>>(x, rws, bconst, sws);
    cls_topk<<<dim3(BB), 256, 0, stream>>>(sws, out, (out_size > LT_OFF) ? 1 : 0);
    write_index<<<dim3(BB * LEFT), 64, 0, stream>>>(out + IDX_OFF, out);
    // Main path.
    gemm_bf16<<<dim3(8 * 18 * 13), 256, 0, stream>>>(xbf, wt1, qkv_b, 18, 0, 0, 99, qkvbf, nullptr);
    transpose_v<<<dim3(7, 2, BB * HH), 256, 0, stream>>>(qkvbf, vtbf);
    attn8<<<dim3(BB * HH), 512, 0, stream>>>(qkvbf, vtbf, atbf);
    gemm_bf16<<<dim3(8 * 6 * 13), 256, 0, stream>>>(atbf, wt2, proj_b, 6, 1, 0, 99,
                                                    nullptr, out + XOUT_OFF);
}

// Round 13
// 311.095 us; speedup vs baseline: 1.5346x; 1.5346x over previous
//
#include <hip/hip_runtime.h>
#include <math.h>

#define BB   64
#define NTOK 197
#define CC   768
#define HH   12
#define DH   64
#define MTOT (BB * NTOK)          // 12608
#define MPAD 12672                // 99*128
#define LEFT 138

// d_out layout (floats, concatenated in return order)
#define XOUT_OFF  0
#define INDEX_OFF 9682944         // B*N*C
#define IDX_OFF   16465920        // + B*138*C
#define CLS_OFF   16474752        // + B*138
#define LT_OFF    16487296        // + B*196

typedef short s8v __attribute__((ext_vector_type(8)));
typedef short s4v __attribute__((ext_vector_type(4)));
typedef float f4v __attribute__((ext_vector_type(4)));

#define GLOAD16(g, l) __builtin_amdgcn_global_load_lds( \
    (const __attribute__((address_space(1))) unsigned int*)(g), \
    (__attribute__((address_space(3))) unsigned int*)(l), 16, 0, 0)

__device__ __forceinline__ unsigned short f2bf(float f) {
    union { float f; unsigned int i; } x; x.f = f;
    unsigned int r = x.i + 0x7FFFu + ((x.i >> 16) & 1u);   // RNE
    return (unsigned short)(r >> 16);
}

// ===========================================================================
// Sub-kernel bodies. Each is the EXACT instruction sequence of its former
// standalone kernel (R5/R10 best-measured versions); only the launch
// packaging changed (blockIdx range branch + shared char buffer).
// ===========================================================================

// fp32 [M,768] -> bf16 [M,768]
__device__ __forceinline__ void convert_x_body(int blk, int tid,
        const float* __restrict__ in, unsigned short* __restrict__ outb)
{
    size_t i = ((size_t)blk * 256 + tid) * 8;
    float4 a = *(const float4*)(in + i);
    float4 b = *(const float4*)(in + i + 4);
    s8v r;
    r[0] = (short)f2bf(a.x); r[1] = (short)f2bf(a.y);
    r[2] = (short)f2bf(a.z); r[3] = (short)f2bf(a.w);
    r[4] = (short)f2bf(b.x); r[5] = (short)f2bf(b.y);
    r[6] = (short)f2bf(b.z); r[7] = (short)f2bf(b.w);
    *(s8v*)(outb + i) = r;
}

// fp32 W [768,N] -> bf16 W^T [N,768]; q<72*24 -> qkv_w else proj_w
__device__ __forceinline__ void transpose_w_body(int q, int tid, char* smem,
        const float* __restrict__ inq, const float* __restrict__ inp,
        unsigned short* __restrict__ outq, unsigned short* __restrict__ outp)
{
    float (*tile)[33] = (float(*)[33])smem;
    const int bi = q % 24;
    int bj = q / 24;
    const float* in; unsigned short* outb; int N;
    if (bj < 72) { in = inq; outb = outq; N = 2304; }
    else         { bj -= 72; in = inp; outb = outp; N = 768; }
    const int tx = tid & 31, ty = tid >> 5;
#pragma unroll
    for (int r = ty; r < 32; r += 8)
        tile[r][tx] = in[(size_t)(bi * 32 + r) * N + bj * 32 + tx];
    __syncthreads();
#pragma unroll
    for (int r = ty; r < 32; r += 8)
        outb[(size_t)(bj * 32 + r) * 768 + bi * 32 + tx] = f2bf(tile[tx][r]);
}

// qr (R5 version, ASSOCIATION ORDER LOAD-BEARING): per-(b,h) block,
// dbuf W_q staging, bias-first c-ascending phase-1 chain, d-ascending
// x/y/z/w phase-2 chain, serial bconst loop.
#define QCH 64
__device__ __forceinline__ void qr_body(int blk, int tid, char* smem,
        const float* __restrict__ x, const float* __restrict__ qkv_w,
        const float* __restrict__ qkv_b, float* __restrict__ rws,
        float* __restrict__ bconst)
{
    const int b = blk / HH, h = blk - b * HH;
    float* x0    = (float*)smem;              // 768 f
    float* q0h   = (float*)(smem + 3072);     // 64 f
    float* wbuf0 = (float*)(smem + 3328);     // 4096 f
    float* wbuf1 = (float*)(smem + 19712);    // 4096 f (ends 36096)
    for (int c = tid; c < CC; c += 256) x0[c] = x[(size_t)b * NTOK * CC + c];
    for (int u = tid; u < QCH * DH; u += 256) {
        int cc = u >> 6, o = u & 63;
        wbuf0[u] = qkv_w[(size_t)cc * 2304 + h * DH + o];
    }
    __syncthreads();
    float acc = 0.f;
    if (tid < DH) acc = qkv_b[h * DH + tid];
    for (int k = 0; k < CC / QCH; ++k) {
        float* wcur  = (k & 1) ? wbuf1 : wbuf0;
        float* wnext = (k & 1) ? wbuf0 : wbuf1;
        if (k + 1 < CC / QCH) {
            const int cbase = (k + 1) * QCH;
            for (int u = tid; u < QCH * DH; u += 256) {
                int cc = u >> 6, o = u & 63;
                wnext[u] = qkv_w[(size_t)(cbase + cc) * 2304 + h * DH + o];
            }
        }
        if (tid < DH) {
            const int cbase = k * QCH;
#pragma unroll
            for (int cc = 0; cc < QCH; ++cc)
                acc = fmaf(x0[cbase + cc], wcur[cc * 64 + tid], acc);
        }
        __syncthreads();
    }
    if (tid < DH) q0h[tid] = acc;
    __syncthreads();
    for (int c = tid; c < CC; c += 256) {
        const float* wrow = qkv_w + (size_t)c * 2304 + CC + h * DH;
        float acc2 = 0.f;
#pragma unroll
        for (int d = 0; d < DH; d += 4) {
            float4 w4 = *(const float4*)(wrow + d);
            acc2 = fmaf(w4.x, q0h[d + 0], acc2);
            acc2 = fmaf(w4.y, q0h[d + 1], acc2);
            acc2 = fmaf(w4.z, q0h[d + 2], acc2);
            acc2 = fmaf(w4.w, q0h[d + 3], acc2);
        }
        rws[((size_t)b * HH + h) * CC + c] = acc2;
    }
    if (tid == 0) {
        float acc3 = 0.f;
        for (int d = 0; d < DH; ++d) acc3 += q0h[d] * qkv_b[CC + h * DH + d];
        bconst[blk] = acc3;
    }
}

// bf16 MFMA GEMM body (R10 version verbatim; As/Bs carved from smem).
__device__ __forceinline__ void gemm_body(int id, int tid, char* smem,
        const unsigned short* __restrict__ A, const unsigned short* __restrict__ BT,
        const float* __restrict__ bias, int ncolt, int mode,
        unsigned short* __restrict__ outb, float* __restrict__ outf)
{
    const int xcd = id & 7;
    const int t = id >> 3;
    const int ct = t % ncolt, s = t / ncolt;
    const int rt = s * 8 + xcd;
    if (rt >= 99) return;
    const int m0 = rt * 128, n0 = ct * 128;

    const int wave = tid >> 6, lane = tid & 63;
    const int quad = lane >> 4, l16 = lane & 15;
    const int rowbase = (wave >> 1) * 64, colbase = (wave & 1) * 64;
    short* As = (short*)smem;                 // 8192 shorts
    short* Bs = (short*)(smem + 16384);       // 8192 shorts

    const int rA   = lane >> 3;
    const int gcol = ((lane & 7) ^ rA) * 8;
    unsigned int agof[4], bgof[4];
#pragma unroll
    for (int i = 0; i < 4; ++i) {
        int c = wave * 4 + i;
        agof[i] = (unsigned int)((m0 + c * 8 + rA) * 768 + gcol);
        bgof[i] = (unsigned int)((n0 + c * 8 + rA) * 768 + gcol);
    }
    int aoff[4], boff[4];
#pragma unroll
    for (int i = 0; i < 4; ++i) {
        aoff[i] = (rowbase + i * 16 + l16) * 64 + ((quad ^ (l16 & 7)) * 8);
        boff[i] = (colbase + i * 16 + l16) * 64 + ((quad ^ (l16 & 7)) * 8);
    }

    f4v acc[4][4];
#pragma unroll
    for (int i = 0; i < 4; ++i)
#pragma unroll
        for (int j = 0; j < 4; ++j) acc[i][j] = (f4v)0.f;

    for (int k0 = 0; k0 < 768; k0 += 64) {
#pragma unroll
        for (int i = 0; i < 4; ++i) {
            int c = wave * 4 + i;
            GLOAD16(A  + agof[i] + k0, &As[c * 512]);
            GLOAD16(BT + bgof[i] + k0, &Bs[c * 512]);
        }
        __syncthreads();
#pragma unroll
        for (int ks = 0; ks < 2; ++ks) {
            const int x = ks * 32;
            s8v af[4], bf[4];
#pragma unroll
            for (int i = 0; i < 4; ++i) af[i] = *(const s8v*)&As[aoff[i] ^ x];
#pragma unroll
            for (int j = 0; j < 4; ++j) bf[j] = *(const s8v*)&Bs[boff[j] ^ x];
#pragma unroll
            for (int i = 0; i < 4; ++i)
#pragma unroll
                for (int j = 0; j < 4; ++j)
                    acc[i][j] = __builtin_amdgcn_mfma_f32_16x16x32_bf16(bf[j], af[i], acc[i][j], 0, 0, 0);
        }
        __syncthreads();
    }

    const int ncols = mode ? 768 : 2304;
#pragma unroll
    for (int i = 0; i < 4; ++i) {
        const int m = m0 + rowbase + i * 16 + l16;
        if (m >= MTOT) continue;
#pragma unroll
        for (int j = 0; j < 4; ++j) {
            const int nb = n0 + colbase + j * 16 + quad * 4;
            float4 b4 = *(const float4*)&bias[nb];
            if (mode == 1) {
                float4 r;
                r.x = acc[i][j][0] + b4.x; r.y = acc[i][j][1] + b4.y;
                r.z = acc[i][j][2] + b4.z; r.w = acc[i][j][3] + b4.w;
                *(float4*)(outf + (size_t)m * ncols + nb) = r;
            } else {
                s4v r;
                r[0] = (short)f2bf(acc[i][j][0] + b4.x);
                r[1] = (short)f2bf(acc[i][j][1] + b4.y);
                r[2] = (short)f2bf(acc[i][j][2] + b4.z);
                r[3] = (short)f2bf(acc[i][j][3] + b4.w);
                *(s4v*)(outb + (size_t)m * ncols + nb) = r;
            }
        }
    }
}

// cls_s (R5 version; fmaf chain c-ascending x/y/z/w, LOAD-BEARING).
__device__ __forceinline__ void cls_s_body(int q, int tid, char* smem,
        const float* __restrict__ x, const float* __restrict__ rws,
        const float* __restrict__ bconst, float* __restrict__ sws)
{
    const int bx = q % 10, b = q / 10;
    float* rl  = (float*)smem;                // HH*772 f, stride 772
    float* bcs = (float*)(smem + 37056);      // HH f
#pragma unroll
    for (int h = 0; h < HH; ++h)
        for (int c = tid; c < CC; c += 256)
            rl[h * 772 + c] = rws[((size_t)b * HH + h) * CC + c];
    if (tid < HH) bcs[tid] = bconst[b * HH + tid];
    __syncthreads();
    const int local = bx * 256 + tid;
    if (local < NTOK * HH) {
        const int tok = local / HH;
        const int h = local - tok * HH;
        const float* xr = x + ((size_t)b * NTOK + tok) * CC;
        const float* rp = rl + h * 772;
        float acc = 0.f;
#pragma unroll 8
        for (int c = 0; c < CC; c += 4) {
            float4 x4 = *(const float4*)(xr + c);
            float4 r4 = *(const float4*)(rp + c);
            acc = fmaf(x4.x, r4.x, acc);
            acc = fmaf(x4.y, r4.y, acc);
            acc = fmaf(x4.z, r4.z, acc);
            acc = fmaf(x4.w, r4.w, acc);
        }
        sws[((size_t)b * HH + h) * NTOK + tok] = (acc + bcs[h]) * 0.125f;
    }
}

// V^T materialization: V [b,tok,h,d] -> vt [bh][d][224], zero-padded.
#define VTS 224
__device__ __forceinline__ void transpose_v_body(int q, int tid, char* smem,
        const unsigned short* __restrict__ qkv, unsigned short* __restrict__ vt)
{
    short (*tile)[33] = (short(*)[33])smem;
    const int bx = q % 7;
    const int by = (q / 7) & 1;
    const int bh = q / 14;
    const int b = bh / HH, h = bh - b * HH;
    const int tx = tid & 31, ty = tid >> 5;
    const unsigned short* vin = qkv + (size_t)b * NTOK * 2304 + 1536 + h * DH;
#pragma unroll
    for (int r = ty; r < 32; r += 8) {
        const int tok = bx * 32 + r;
        tile[r][tx] = (tok < NTOK) ? (short)vin[(size_t)tok * 2304 + by * 32 + tx] : (short)0;
    }
    __syncthreads();
#pragma unroll
    for (int r = ty; r < 32; r += 8) {
        const int d = by * 32 + r;
        vt[((size_t)bh * DH + d) * VTS + bx * 32 + tx] = tile[tx][r];
    }
}

// cls_topk (exact softmax/mean/bitonic code, LOAD-BEARING).
__device__ __forceinline__ void cls_topk_body(int b, int tid, char* smem,
        const float* __restrict__ sws, float* __restrict__ out, int write_lt)
{
    const int wave = tid >> 6, lane = tid & 63;
    float (*sbuf)[208] = (float(*)[208])smem;             // 9984 B
    float (*pm)[208]   = (float(*)[208])(smem + 9984);    // 3328 B
    float* vals        = (float*)(smem + 13312);          // 1024 B
    int*   idxs        = (int*)(smem + 14336);            // 1024 B

    for (int jj = lane; jj < 208; jj += 64) pm[wave][jj] = 0.f;
    if (tid < NTOK) {
#pragma unroll
        for (int h = 0; h < HH; ++h)
            sbuf[h][tid] = sws[((size_t)b * HH + h) * NTOK + tid];
    }
    __syncthreads();

    for (int h = wave; h < HH; h += 4) {
        float sv[4], ev[4];
        float mx = -1e30f;
#pragma unroll
        for (int t = 0; t < 4; ++t) {
            int j = lane + 64 * t;
            sv[t] = (j < NTOK) ? sbuf[h][j] : -1e30f;
            mx = fmaxf(mx, sv[t]);
        }
#pragma unroll
        for (int off = 1; off < 64; off <<= 1) mx = fmaxf(mx, __shfl_xor(mx, off, 64));
        float sm = 0.f;
#pragma unroll
        for (int t = 0; t < 4; ++t) {
            int j = lane + 64 * t;
            ev[t] = (j < NTOK) ? expf(sv[t] - mx) : 0.f;
            sm += ev[t];
        }
#pragma unroll
        for (int off = 1; off < 64; off <<= 1) sm += __shfl_xor(sm, off, 64);
#pragma unroll
        for (int t = 0; t < 4; ++t) {
            int j = lane + 64 * t;
            if (j < NTOK) pm[wave][j] += ev[t] / sm;
        }
    }
    __syncthreads();

    float v = -INFINITY;
    int id = 256 + tid;
    if (tid < NTOK - 1) {
        int j = tid + 1;
        float s = ((pm[0][j] + pm[1][j]) + (pm[2][j] + pm[3][j])) * (1.f / 12.f);
        v = s; id = tid;
        out[CLS_OFF + (size_t)b * (NTOK - 1) + tid] = s;
    }
    vals[tid] = v; idxs[tid] = id;
    __syncthreads();

    for (int k = 2; k <= 256; k <<= 1) {
        for (int j = k >> 1; j > 0; j >>= 1) {
            int ixj = tid ^ j;
            if (ixj > tid) {
                float va = vals[tid], vb2 = vals[ixj];
                int ia = idxs[tid], ib = idxs[ixj];
                bool aLess = (va > vb2) || (va == vb2 && ia < ib);
                bool dir = ((tid & k) == 0);
                if (dir != aLess) {
                    vals[tid] = vb2; vals[ixj] = va;
                    idxs[tid] = ib;  idxs[ixj] = ia;
                }
            }
            __syncthreads();
        }
    }

    if (tid < LEFT) out[IDX_OFF + (size_t)b * LEFT + tid] = (float)idxs[tid];
    if (write_lt && b == 0 && tid == 0) out[LT_OFF] = (float)LEFT;
}

// write_index (256-thread variant: 192 lanes x one float4 per row).
__device__ __forceinline__ void write_index_body(int row, int tid,
        const float* __restrict__ idx_in, float* __restrict__ out)
{
    const float v = idx_in[row];
    if (tid < 192) {
        float4 r; r.x = v; r.y = v; r.z = v; r.w = v;
        *(float4*)(out + INDEX_OFF + (size_t)row * CC + tid * 4) = r;
    }
}

// ===========================================================================
// Fat kernels: co-schedule independent sub-kernels in one dispatch so
// latency-bound waves fill the issue slots compute-bound waves leave idle.
// Branch is block-uniform (on blockIdx.x) -> __syncthreads stays legal.
// ===========================================================================
#define PRE_QR 768
#define PRE_CV 4728
#define PRE_TW 2304

__global__ __launch_bounds__(256)
void fat_pre(const float* __restrict__ x, const float* __restrict__ qkv_w,
             const float* __restrict__ qkv_b, const float* __restrict__ proj_w,
             unsigned short* __restrict__ xbf, unsigned short* __restrict__ wt1,
             unsigned short* __restrict__ wt2, float* __restrict__ rws,
             float* __restrict__ bconst)
{
    __shared__ __align__(16) char smem[36096];
    const int id = blockIdx.x, tid = threadIdx.x;
    if (id < PRE_QR)
        qr_body(id, tid, smem, x, qkv_w, qkv_b, rws, bconst);
    else if (id < PRE_QR + PRE_CV)
        convert_x_body(id - PRE_QR, tid, x, xbf);
    else
        transpose_w_body(id - PRE_QR - PRE_CV, tid, smem, qkv_w, proj_w, wt1, wt2);
}

#define QKV_GEMM (8 * 18 * 13)    // 1872

__global__ __launch_bounds__(256, 3)
void fat_qkv(const unsigned short* __restrict__ xbf, const unsigned short* __restrict__ wt1,
             const float* __restrict__ qkv_b, unsigned short* __restrict__ qkvbf,
             const float* __restrict__ x, const float* __restrict__ rws,
             const float* __restrict__ bconst, float* __restrict__ sws)
{
    __shared__ __align__(16) char smem[37104];
    const int id = blockIdx.x, tid = threadIdx.x;
    if (id < QKV_GEMM)
        gemm_body(id, tid, smem, xbf, wt1, qkv_b, 18, 0, qkvbf, nullptr);
    else
        cls_s_body(id - QKV_GEMM, tid, smem, x, rws, bconst, sws);
}

__global__ __launch_bounds__(256)
void fat_tv(const unsigned short* __restrict__ qkvbf, unsigned short* __restrict__ vt,
            const float* __restrict__ sws, float* __restrict__ out, int write_lt)
{
    __shared__ __align__(16) char smem[15360];
    const int id = blockIdx.x, tid = threadIdx.x;
    if (id < 64)
        cls_topk_body(id, tid, smem, sws, out, write_lt);
    else
        transpose_v_body(id - 64, tid, smem, qkvbf, vt);
}

#define PROJ_GEMM (8 * 6 * 13)    // 624

__global__ __launch_bounds__(256, 3)
void fat_proj(const unsigned short* __restrict__ atbf, const unsigned short* __restrict__ wt2,
              const float* __restrict__ proj_b, float* __restrict__ outf,
              const float* __restrict__ idx_in, float* __restrict__ out)
{
    __shared__ __align__(16) char smem[32768];
    const int id = blockIdx.x, tid = threadIdx.x;
    if (id < PROJ_GEMM)
        gemm_body(id, tid, smem, atbf, wt2, proj_b, 6, 1, nullptr, outf);
    else
        write_index_body(id - PROJ_GEMM, tid, idx_in, out);
}

// ---------------------------------------------------------------------------
// MFMA attention (R10/R11 attn_mfma4 verbatim — measured 51.9us, refcheck'd).
// ---------------------------------------------------------------------------
#define PSTR 226

__global__ __launch_bounds__(256, 2)
void attn_mfma4(const unsigned short* __restrict__ qkv, const unsigned short* __restrict__ vt,
                unsigned short* __restrict__ attnbf)
{
    const int bh = blockIdx.x;           // 0..767
    const int g  = blockIdx.y;           // 0..3
    const int b = bh / HH, h = bh - b * HH;
    const int tid = threadIdx.x;
    const int wave = tid >> 6, lane = tid & 63;
    const int quad = lane >> 4, l16 = lane & 15;
    __shared__ __align__(16) short Ks[NTOK * 64];   // 25.2 KB, XOR-swizzled
    __shared__ short Ps[4][16 * PSTR];              // 28.9 KB

    const unsigned short* qg = qkv + (size_t)b * NTOK * 2304 + h * DH;
    const unsigned short* kg = qg + 768;
    const unsigned short* vtb = vt + (size_t)bh * DH * VTS;

    for (int u = tid; u < NTOK * 8; u += 256) {
        const int row = u >> 3, seg = u & 7;
        *(s8v*)&Ks[row * 64 + (seg ^ (row & 7)) * 8] =
            *(const s8v*)(kg + (size_t)row * 2304 + seg * 8);
    }
    __syncthreads();

    const int strip = g * 4 + wave;      // 0..15; 13..15 idle
    if (strip >= 13) return;

    const int mq = min(strip * 16 + l16, NTOK - 1);
    const s8v aq0 = *(const s8v*)(qg + (size_t)mq * 2304 + quad * 8);
    const s8v aq1 = *(const s8v*)(qg + (size_t)mq * 2304 + 32 + quad * 8);

    f4v sacc[14];
#pragma unroll
    for (int j = 0; j < 14; ++j) sacc[j] = (f4v)0.f;
    __builtin_amdgcn_s_setprio(1);
#pragma unroll
    for (int j = 0; j < 14; ++j) {
        const int kt = min(j * 16 + l16, NTOK - 1);
        s8v bk0 = *(const s8v*)&Ks[kt * 64 + ((quad       ^ (kt & 7)) * 8)];
        s8v bk1 = *(const s8v*)&Ks[kt * 64 + (((quad + 4) ^ (kt & 7)) * 8)];
        sacc[j] = __builtin_amdgcn_mfma_f32_16x16x32_bf16(bk0, aq0, sacc[j], 0, 0, 0);
        sacc[j] = __builtin_amdgcn_mfma_f32_16x16x32_bf16(bk1, aq1, sacc[j], 0, 0, 0);
    }
    __builtin_amdgcn_s_setprio(0);

    s8v bvr[7][4];
#pragma unroll
    for (int t = 0; t < 7; ++t) {
        const int ko = t * 32 + quad * 8;
#pragma unroll
        for (int j = 0; j < 4; ++j)
            bvr[t][j] = *(const s8v*)(vtb + (size_t)(j * 16 + l16) * VTS + ko);
    }

    float mx = -1e30f;
#pragma unroll
    for (int j = 0; j < 14; ++j)
#pragma unroll
        for (int r = 0; r < 4; ++r) {
            const int key = j * 16 + quad * 4 + r;
            float s = (key < NTOK) ? sacc[j][r] * 0.125f : -1e30f;
            sacc[j][r] = s;
            mx = fmaxf(mx, s);
        }
    mx = fmaxf(mx, __shfl_xor(mx, 16, 64));
    mx = fmaxf(mx, __shfl_xor(mx, 32, 64));

    float sm = 0.f;
#pragma unroll
    for (int j = 0; j < 14; ++j) {
        s4v pk;
#pragma unroll
        for (int r = 0; r < 4; ++r) {
            const int key = j * 16 + quad * 4 + r;
            float p = (key < NTOK) ? __expf(sacc[j][r] - mx) : 0.f;
            sm += p;
            pk[r] = (short)f2bf(p);
        }
        *(s4v*)&Ps[wave][l16 * PSTR + j * 16 + quad * 4] = pk;
    }
    sm += __shfl_xor(sm, 16, 64);
    sm += __shfl_xor(sm, 32, 64);
    const float rcp = 1.f / sm;

    f4v oacc[4];
#pragma unroll
    for (int j = 0; j < 4; ++j) oacc[j] = (f4v)0.f;
    __builtin_amdgcn_s_setprio(1);
#pragma unroll
    for (int t = 0; t < 7; ++t) {
        const int ko = t * 32 + quad * 8;
        s8v ap = *(const s8v*)&Ps[wave][l16 * PSTR + ko];
#pragma unroll
        for (int j = 0; j < 4; ++j)
            oacc[j] = __builtin_amdgcn_mfma_f32_16x16x32_bf16(bvr[t][j], ap, oacc[j], 0, 0, 0);
    }
    __builtin_amdgcn_s_setprio(0);
    const int qrow = strip * 16 + l16;
    if (qrow < NTOK) {
#pragma unroll
        for (int j = 0; j < 4; ++j) {
            s4v o4;
#pragma unroll
            for (int r = 0; r < 4; ++r) o4[r] = (short)f2bf(oacc[j][r] * rcp);
            *(s4v*)&attnbf[((size_t)b * NTOK + qrow) * 768 + h * DH + j * 16 + quad * 4] = o4;
        }
    }
}

// ---------------------------------------------------------------------------
extern "C" void kernel_launch(void* const* d_in, const int* in_sizes, int n_in,
                              void* d_out, int out_size, void* d_ws, size_t ws_size,
                              hipStream_t stream)
{
    const float* x      = (const float*)d_in[0];
    const float* qkv_w  = (const float*)d_in[1];
    const float* qkv_b  = (const float*)d_in[2];
    const float* proj_w = (const float*)d_in[3];
    const float* proj_b = (const float*)d_in[4];
    float* out = (float*)d_out;

    char* w = (char*)d_ws;
    unsigned short* xbf   = (unsigned short*)w; w += (size_t)MPAD * CC * 2;
    unsigned short* wt1   = (unsigned short*)w; w += (size_t)3 * CC * CC * 2;
    unsigned short* wt2   = (unsigned short*)w; w += (size_t)CC * CC * 2;
    unsigned short* qkvbf = (unsigned short*)w; w += (size_t)MTOT * 3 * CC * 2;
    unsigned short* atbf  = (unsigned short*)w; w += (size_t)MPAD * CC * 2;
    float* rws    = (float*)w; w += (size_t)BB * HH * CC * 4;
    float* bconst = (float*)w; w += (size_t)BB * HH * 4;
    float* sws    = (float*)w; w += (size_t)BB * HH * NTOK * 4;
    // vt aliases xbf+wt1 (22.0MB <= 23.0MB): last reader (fat_qkv's gemm)
    // completes before fat_tv's transpose_v writes it (stream-serial).
    unsigned short* vtbf  = (unsigned short*)d_ws;

    // 1. qr || convert_x || transpose_w  (all read only inputs)
    fat_pre<<<dim3(PRE_QR + PRE_CV + PRE_TW), 256, 0, stream>>>(
        x, qkv_w, qkv_b, proj_w, xbf, wt1, wt2, rws, bconst);
    // 2. QKV GEMM || cls_s
    fat_qkv<<<dim3(QKV_GEMM + 640), 256, 0, stream>>>(
        xbf, wt1, qkv_b, qkvbf, x, rws, bconst, sws);
    // 3. cls_topk || transpose_v
    fat_tv<<<dim3(64 + 7 * 2 * BB * HH), 256, 0, stream>>>(
        qkvbf, vtbf, sws, out, (out_size > LT_OFF) ? 1 : 0);
    // 4. attention
    attn_mfma4<<<dim3(BB * HH, 4), 256, 0, stream>>>(qkvbf, vtbf, atbf);
    // 5. proj GEMM || write_index
    fat_proj<<<dim3(PROJ_GEMM + BB * LEFT), 256, 0, stream>>>(
        atbf, wt2, proj_b, out + XOUT_OFF, out + IDX_OFF, out);
}